// Round 11
// baseline (461.045 us; speedup 1.0000x reference)
//
#include <hip/hip_runtime.h>
#include <math.h>

#define N_ROWS 32768
#define KCODES 1024
#define DIM 64
#define OUT_Q 1
#define OUT_PERP 2097153
#define OUT_ENC 2097154
#define GAP_QUANTA 64u   // 64 * 2^-21 ~ 3.05e-5 >> bf16-split dot err (~1e-6)

using short8 = __attribute__((ext_vector_type(8))) short;   // 8 bf16 (4 VGPR)
using f32x4  = __attribute__((ext_vector_type(4))) float;
typedef float f32x2 __attribute__((ext_vector_type(2)));

__device__ __forceinline__ unsigned umin_(unsigned a, unsigned b){return a<b?a:b;}
__device__ __forceinline__ unsigned umax_(unsigned a, unsigned b){return a>b?a:b;}
// RTNE float->bf16
__device__ __forceinline__ unsigned short f2bf(float f){
    unsigned u = __float_as_uint(f);
    unsigned r = (u + 0x7FFFu + ((u >> 16) & 1u)) >> 16;
    return (unsigned short)r;
}
__device__ __forceinline__ float bf2f(unsigned short h){
    return __uint_as_float(((unsigned)h) << 16);
}

// ---------------------------------------------------------------------------
// P: prep (64 blocks; one thread per (code, float4-chunk)).
// sqnB21[k] = (0.25 + 0.5||e_k||^2)*2^21 (fp64, 16-lane shfl reduce);
// codebook bf16-split packed in MFMA-fragment order (epack); zero counts.
// ---------------------------------------------------------------------------
__global__ __launch_bounds__(256) void vq_prep_kernel(
    const float* __restrict__ emb, float* __restrict__ sqnB21,
    unsigned short* __restrict__ epack, int* __restrict__ counts) {
    int t = blockIdx.x * 256 + threadIdx.x;  // 16384 threads
    int k = t >> 4, q = t & 15;
    if (t < KCODES) counts[t] = 0;
    int tile = k >> 4, col = k & 15;
    float4 v = ((const float4*)emb)[t];      // = emb[k*64 + q*4 ..]
    unsigned short h0=f2bf(v.x), h1=f2bf(v.y), h2=f2bf(v.z), h3=f2bf(v.w);
    unsigned short l0=f2bf(v.x-bf2f(h0)), l1=f2bf(v.y-bf2f(h1)),
                   l2=f2bf(v.z-bf2f(h2)), l3=f2bf(v.w-bf2f(h3));
    unsigned* up = (unsigned*)epack;
    unsigned idx = tile * 1024u + (q >> 1) * 64u + col * 4u + (q & 1) * 2u;
    up[idx]       = (unsigned)h0 | ((unsigned)h1 << 16);
    up[idx + 1]   = (unsigned)h2 | ((unsigned)h3 << 16);
    up[idx + 512] = (unsigned)l0 | ((unsigned)l1 << 16);
    up[idx + 513] = (unsigned)l2 | ((unsigned)l3 << 16);
    double s = (double)v.x*v.x + (double)v.y*v.y +
               (double)v.z*v.z + (double)v.w*v.w;
    s += __shfl_xor(s, 1);
    s += __shfl_xor(s, 2);
    s += __shfl_xor(s, 4);
    s += __shfl_xor(s, 8);
    if (q == 0) sqnB21[k] = (float)((0.25 + 0.5 * s) * 2097152.0);
}

// ---------------------------------------------------------------------------
// A: fused MFMA argmin + K-merge + flag + in-block exact fp64 recheck.
// Block = 16 rows; wave w scans chunk w (256 codes, 16 tiles of 16 codes).
// Per tile: 6 mfma_16x16x32_bf16 (hh+hl+lh over two K=32 halves of D=64),
// B-frags from epack (1KB contiguous wave-loads). C layout (m89):
// col=lane&15, row=(lane>>4)*4+reg. Packed key (dist<<10|code) best/second.
// In-wave xor-reduce -> LDS merge across waves -> idx + near-tie flag ->
// flagged rows (~3%) get an exact fp64 re-scan by all 256 threads.
// Writes ONLY idxp. No pairP, no separate flag/recheck dispatches.
// ---------------------------------------------------------------------------
__global__ __launch_bounds__(256, 4) void vq_argmin_mfma(
    const float* __restrict__ x, const float* __restrict__ emb,
    const unsigned short* __restrict__ epack,
    const float* __restrict__ sqnB21, int* __restrict__ idxp) {
    __shared__ unsigned sbb[4][16], sss[4][16];
    __shared__ float xrow[64];
    __shared__ double rD[4];
    __shared__ int rI[4], frows[16], fcnt;
    int tid = threadIdx.x;
    int bi = blockIdx.x;          // 2048 blocks, 16 rows each
    int lane = tid & 63;
    int w = tid >> 6;             // wave = K-chunk
    int col = lane & 15;
    int g = lane >> 4;
    if (tid == 0) fcnt = 0;
    int n = bi * 16 + col;
    int xbase = (n >> 12) * 262144 + (n & 4095);

    short8 ah0, al0, ah1, al1;
#pragma unroll
    for (int j = 0; j < 8; ++j) {
        float v0 = x[xbase + (g * 8 + j) * 4096];
        unsigned short h0 = f2bf(v0);
        ah0[j] = (short)h0; al0[j] = (short)f2bf(v0 - bf2f(h0));
        float v1 = x[xbase + (32 + g * 8 + j) * 4096];
        unsigned short h1 = f2bf(v1);
        ah1[j] = (short)h1; al1[j] = (short)f2bf(v1 - bf2f(h1));
    }

    unsigned best[4] = {~0u, ~0u, ~0u, ~0u}, sec[4] = {~0u, ~0u, ~0u, ~0u};
    const int tbase = w * 16;     // 16 tiles per chunk
#pragma unroll 4
    for (int tt = 0; tt < 16; ++tt) {
        int tile = tbase + tt;
        int code = tile * 16 + col;
        const short8* bp = (const short8*)(epack + (size_t)tile * 2048);
        short8 bh0 = bp[lane];        // h, d 0..31   (s=g)
        short8 bh1 = bp[64 + lane];   // h, d 32..63
        short8 bl0 = bp[128 + lane];  // l, d 0..31
        short8 bl1 = bp[192 + lane];  // l, d 32..63
        float sqv = sqnB21[code];
        f32x4 a0 = {0.f, 0.f, 0.f, 0.f}, a1 = {0.f, 0.f, 0.f, 0.f};
        a0 = __builtin_amdgcn_mfma_f32_16x16x32_bf16(ah0, bh0, a0, 0, 0, 0);
        a0 = __builtin_amdgcn_mfma_f32_16x16x32_bf16(ah1, bh1, a0, 0, 0, 0);
        a1 = __builtin_amdgcn_mfma_f32_16x16x32_bf16(ah0, bl0, a1, 0, 0, 0);
        a1 = __builtin_amdgcn_mfma_f32_16x16x32_bf16(al0, bh0, a1, 0, 0, 0);
        a1 = __builtin_amdgcn_mfma_f32_16x16x32_bf16(ah1, bl1, a1, 0, 0, 0);
        a1 = __builtin_amdgcn_mfma_f32_16x16x32_bf16(al1, bh1, a1, 0, 0, 0);
#pragma unroll
        for (int r = 0; r < 4; ++r) {
            float s = a0[r] + a1[r];
            unsigned u = (unsigned)fmaf(s, -2097152.0f, sqv);
            unsigned pk = (u << 10) | (unsigned)code;
            unsigned t = umax_(pk, best[r]);
            sec[r] = umin_(sec[r], t);
            best[r] = umin_(best[r], pk);
        }
    }
    // xor-reduce over the 16 code-columns within each 16-lane group
#pragma unroll
    for (int st = 1; st < 16; st <<= 1) {
#pragma unroll
        for (int r = 0; r < 4; ++r) {
            unsigned ob = __shfl_xor(best[r], st);
            unsigned os = __shfl_xor(sec[r], st);
            sec[r] = umin_(umin_(sec[r], os), umax_(best[r], ob));
            best[r] = umin_(best[r], ob);
        }
    }
    if (col == 0) {
#pragma unroll
        for (int r = 0; r < 4; ++r) {
            sbb[w][g * 4 + r] = best[r];
            sss[w][g * 4 + r] = sec[r];
        }
    }
    __syncthreads();
    // merge the 4 chunks per row; write idx; flag near-ties in-block
    if (tid < 16) {
        unsigned b = sbb[0][tid], s = sss[0][tid];
#pragma unroll
        for (int cc = 1; cc < 4; ++cc) {
            unsigned qb = sbb[cc][tid], qs = sss[cc][tid];
            s = umin_(umin_(s, qs), umax_(b, qb));
            b = umin_(b, qb);
        }
        idxp[bi * 16 + tid] = (int)(b & 1023u);
        if (((s >> 10) - (b >> 10)) < GAP_QUANTA) {
            int pos = atomicAdd(&fcnt, 1);
            frows[pos] = tid;
        }
    }
    __syncthreads();
    // exact fp64 re-scan of flagged rows (usually 0-1 per block)
    for (int i = 0; i < fcnt; ++i) {
        int row = frows[i];
        int n2 = bi * 16 + row;
        int xo = (n2 >> 12) * 262144 + (n2 & 4095);
        if (tid < 64) xrow[tid] = x[xo + tid * 4096];
        __syncthreads();
        double bu = 1e300;
        int bk = 0;
#pragma unroll
        for (int j = 0; j < 4; ++j) {
            int k = tid + 256 * j;   // ascending per thread
            const float4* e4 = (const float4*)(emb + k * DIM);
            double u = 0.0;
#pragma unroll
            for (int q = 0; q < 16; ++q) {
                float4 ev = e4[q];
                double e0 = ev.x, e1 = ev.y, e2 = ev.z, e3 = ev.w;
                u += e0 * (0.5 * e0 - (double)xrow[q * 4 + 0]);
                u += e1 * (0.5 * e1 - (double)xrow[q * 4 + 1]);
                u += e2 * (0.5 * e2 - (double)xrow[q * 4 + 2]);
                u += e3 * (0.5 * e3 - (double)xrow[q * 4 + 3]);
            }
            if (u < bu) { bu = u; bk = k; }   // strict: j asc => lowest k
        }
        // wave reduce (lowest index on exact ties)
        for (int off = 32; off > 0; off >>= 1) {
            double ou = __shfl_down(bu, off);
            int ok = __shfl_down(bk, off);
            if (ou < bu || (ou == bu && ok < bk)) { bu = ou; bk = ok; }
        }
        if (lane == 0) { rD[w] = bu; rI[w] = bk; }
        __syncthreads();
        if (tid == 0) {
            double fu = rD[0]; int fk = rI[0];
#pragma unroll
            for (int ww = 1; ww < 4; ++ww) {
                if (rD[ww] < fu || (rD[ww] == fu && rI[ww] < fk)) {
                    fu = rD[ww]; fk = rI[ww];
                }
            }
            idxp[n2] = fk;
        }
        __syncthreads();
    }
}

// ---------------------------------------------------------------------------
// C: fused outputs — quantized (NCHW) + per-block loss partial + counts +
// FULL one-hot rows (no pre-fill anywhere; plain stores stream through L2).
// Phase 1: 16 rows x 16 d-groups. Phase 2: full-wave row sweeps (512B
// contiguous per store instruction), 4 rows/wave.
// ---------------------------------------------------------------------------
__global__ __launch_bounds__(256) void vq_outputs_kernel(
    const float* __restrict__ x, const float* __restrict__ emb,
    const int* __restrict__ idxp, float* __restrict__ out,
    int* __restrict__ counts, double* __restrict__ lossp) {
    int tid = threadIdx.x;
    int bi = blockIdx.x;
    int r = tid & 15;
    int dg = tid >> 4;
    int n = bi * 16 + r;
    int ix = idxp[n];
    int xoff = (n >> 12) * 262144 + (n & 4095);
    float4 ev = *(const float4*)(emb + ix * DIM + dg * 4);
    float* qp = out + OUT_Q + xoff;
    float lsum = 0.f;
#pragma unroll
    for (int j = 0; j < 4; ++j) {
        int d = dg * 4 + j;
        float e = (&ev.x)[j];
        float xval = x[xoff + d * 4096];
        float df = e - xval;
        lsum += df * df;
        qp[d * 4096] = e;
    }
    if (dg == 0) atomicAdd(&counts[ix], 1);
    double ls = (double)lsum;
    for (int off = 32; off > 0; off >>= 1) ls += __shfl_down(ls, off);
    __shared__ double red[4];
    if ((tid & 63) == 0) red[tid >> 6] = ls;
    __syncthreads();
    if (tid == 0) lossp[bi] = red[0] + red[1] + red[2] + red[3];

    // ---- phase 2: full-wave row sweeps, 512B contiguous plain stores
    float* enc = out + OUT_ENC;
    int lane = tid & 63;
    int w = tid >> 6;
    int lane2 = lane * 2;
#pragma unroll
    for (int i = 0; i < 4; ++i) {
        int row = bi * 16 + w * 4 + i;
        int iv = idxp[row];   // same address across wave -> broadcast
        f32x2* erow = (f32x2*)(enc + (size_t)row * 1024);
#pragma unroll
        for (int j = 0; j < 8; ++j) {
            int c2 = lane2 + 128 * j;
            f32x2 v;
            v.x = (c2 == iv) ? 1.0f : 0.0f;
            v.y = (c2 + 1 == iv) ? 1.0f : 0.0f;
            erow[lane + 64 * j] = v;
        }
    }
}

// ---------------------------------------------------------------------------
// D: perplexity + loss scalars.
// ---------------------------------------------------------------------------
__global__ void vq_finalize_kernel(const int* __restrict__ counts,
                                   const double* __restrict__ lossp,
                                   float* __restrict__ out) {
    __shared__ double redv[16], redl[16];
    int t = threadIdx.x;  // 1024
    double p = (double)counts[t] / 32768.0;
    double v = p * log(p + 1e-10);
    double l = lossp[t] + lossp[t + 1024];
    for (int off = 32; off > 0; off >>= 1) {
        v += __shfl_down(v, off);
        l += __shfl_down(l, off);
    }
    if ((t & 63) == 0) { redv[t >> 6] = v; redl[t >> 6] = l; }
    __syncthreads();
    if (t == 0) {
        double sv = 0.0, sl = 0.0;
#pragma unroll
        for (int i = 0; i < 16; ++i) { sv += redv[i]; sl += redl[i]; }
        out[OUT_PERP] = (float)exp(-sv);
        out[0] = (float)(sl * (1.25 / 2097152.0));
    }
}

// ---------------------------------------------------------------------------
extern "C" void kernel_launch(void* const* d_in, const int* in_sizes, int n_in,
                              void* d_out, int out_size, void* d_ws,
                              size_t ws_size, hipStream_t stream) {
    (void)in_sizes; (void)n_in; (void)out_size; (void)ws_size;
    const float* x = (const float*)d_in[0];
    const float* emb = (const float*)d_in[1];
    float* out = (float*)d_out;
    char* p = (char*)d_ws;

    int* idxp = (int*)p;        p += 131072;
    float* sqnB21 = (float*)p;  p += 4096;
    int* counts = (int*)p;      p += 4096;
    double* lossp = (double*)p;           // 16 KB (2048 per-block partials)

    // epack lives in the enc output region (rows 0..64 are fully rewritten
    // by vq_outputs_kernel afterwards): enc+6 floats -> 16B-aligned, 256 KB.
    float* enc = out + OUT_ENC;
    unsigned short* epack = (unsigned short*)(enc + 6);

    vq_prep_kernel<<<64, 256, 0, stream>>>(emb, sqnB21, epack, counts);
    vq_argmin_mfma<<<2048, 256, 0, stream>>>(x, emb, epack, sqnB21, idxp);
    vq_outputs_kernel<<<2048, 256, 0, stream>>>(x, emb, idxp, out, counts,
                                                lossp);
    vq_finalize_kernel<<<1, 1024, 0, stream>>>(counts, lossp, out);
}

// Round 12
// 101.357 us; speedup vs baseline: 4.5487x; 4.5487x over previous
//
#include <hip/hip_runtime.h>
#include <math.h>

#define N_ROWS 32768
#define KCODES 1024
#define DIM 64
#define OUT_Q 1
#define OUT_PERP 2097153
#define OUT_ENC 2097154
#define ENC_FLOATS 33554432
#define KSPLIT 4         // code chunks; wave scans KCODES/KSPLIT codes
#define CPCH 256         // codes per chunk
#define GAP_QUANTA 64u   // 64 * 2^-21 ~ 3.05e-5 >> bf16-split dot err (~1e-6)
#define ZBLOCKS 512      // dedicated zero-fill blocks inside argmin dispatch

// scratch layout inside enc region (floats): [0,6) pad, [6,65542) epack,
// [65542,327686) pairP, zstart=327690 (16B-aligned); 2-float tail at end.
#define SCR_FLOATS 327690
#define ZSLOTS 8306685   // (ENC_FLOATS - SCR_FLOATS - 2) / 4

using short8 = __attribute__((ext_vector_type(8))) short;   // 8 bf16 (4 VGPR)
using f32x4  = __attribute__((ext_vector_type(4))) float;
typedef float f32x2 __attribute__((ext_vector_type(2)));

__device__ __forceinline__ unsigned umin_(unsigned a, unsigned b){return a<b?a:b;}
__device__ __forceinline__ unsigned umax_(unsigned a, unsigned b){return a>b?a:b;}
// RTNE float->bf16
__device__ __forceinline__ unsigned short f2bf(float f){
    unsigned u = __float_as_uint(f);
    unsigned r = (u + 0x7FFFu + ((u >> 16) & 1u)) >> 16;
    return (unsigned short)r;
}
__device__ __forceinline__ float bf2f(unsigned short h){
    return __uint_as_float(((unsigned)h) << 16);
}

// ---------------------------------------------------------------------------
// P: prep (64 blocks; one thread per (code, float4-chunk)).
// sqnB21[k] = (0.25 + 0.5||e_k||^2)*2^21 (fp64, 16-lane shfl reduce);
// codebook bf16-split packed in MFMA-fragment order (epack).
// Also zeroes counts/flagcount.
// ---------------------------------------------------------------------------
__global__ __launch_bounds__(256) void vq_prep_kernel(
    const float* __restrict__ emb, float* __restrict__ sqnB21,
    unsigned short* __restrict__ epack, int* __restrict__ counts,
    int* __restrict__ flagcount) {
    int t = blockIdx.x * 256 + threadIdx.x;  // 16384 threads
    int k = t >> 4, q = t & 15;
    if (t < KCODES) counts[t] = 0;
    if (t == 0) flagcount[0] = 0;
    int tile = k >> 4, col = k & 15;
    float4 v = ((const float4*)emb)[t];      // = emb[k*64 + q*4 ..]
    unsigned short h0=f2bf(v.x), h1=f2bf(v.y), h2=f2bf(v.z), h3=f2bf(v.w);
    unsigned short l0=f2bf(v.x-bf2f(h0)), l1=f2bf(v.y-bf2f(h1)),
                   l2=f2bf(v.z-bf2f(h2)), l3=f2bf(v.w-bf2f(h3));
    unsigned* up = (unsigned*)epack;
    unsigned idx = tile * 1024u + (q >> 1) * 64u + col * 4u + (q & 1) * 2u;
    up[idx]       = (unsigned)h0 | ((unsigned)h1 << 16);
    up[idx + 1]   = (unsigned)h2 | ((unsigned)h3 << 16);
    up[idx + 512] = (unsigned)l0 | ((unsigned)l1 << 16);
    up[idx + 513] = (unsigned)l2 | ((unsigned)l3 << 16);
    double s = (double)v.x*v.x + (double)v.y*v.y +
               (double)v.z*v.z + (double)v.w*v.w;
    s += __shfl_xor(s, 1);
    s += __shfl_xor(s, 2);
    s += __shfl_xor(s, 4);
    s += __shfl_xor(s, 8);
    if (q == 0) sqnB21[k] = (float)((0.25 + 0.5 * s) * 2097152.0);
}

// ---------------------------------------------------------------------------
// A: MFMA argmin with LDS-STAGED codebook + block-specialized enc zero-fill.
// Compute blocks (4/5): block = 64 rows x 1 chunk; the chunk's 16 tiles are
// staged into LDS in two 32KB halves (cooperative float4 copy, keeps 4
// blocks/CU), B-frags then come from ds_read_b128 (ordered, pipelineable,
// no L2 latency in the inner loop). Packed-key best/second per row.
// Specialist blocks (1/5): stream the 127MB enc zero region.
// ---------------------------------------------------------------------------
__global__ __launch_bounds__(256, 4) void vq_argmin_mfma(
    const float* __restrict__ x, const unsigned short* __restrict__ epack,
    const float* __restrict__ sqnB21, uint2* __restrict__ pairP,
    float* __restrict__ enc) {
    int bid = blockIdx.x;
    if ((bid % 5) == 4) {
        // ---- zero-fill specialist block
        int zid = bid / 5;                       // 0..511
        unsigned t0 = zid * 256 + threadIdx.x;   // 131072 threads
        f32x4* zbase = (f32x4*)(enc + SCR_FLOATS);
        const f32x4 zz = {0.f, 0.f, 0.f, 0.f};
#pragma unroll 8
        for (int i = 0; i < 64; ++i) {
            unsigned slot = t0 + 131072u * i;
            if (slot < ZSLOTS) zbase[slot] = zz;
        }
        return;
    }
    __shared__ short8 elds[8 * 256];             // 32 KB: 8 tiles
    int tid = threadIdx.x;
    int argid = bid - bid / 5;                   // 0..2047
    int lane = tid & 63;
    int w = tid >> 6;
    int col = lane & 15;       // A row for loads / C col (code) in epilogue
    int g = lane >> 4;         // k-group: frag holds k = g*8 + j
    int rb = argid >> 2;               // row-block 0..511
    int c = argid & (KSPLIT - 1);      // code chunk 0..3
    int n = rb * 64 + w * 16 + col;
    int xbase = (n >> 12) * 262144 + (n & 4095);

    short8 ah0, al0, ah1, al1;
#pragma unroll
    for (int j = 0; j < 8; ++j) {
        float v0 = x[xbase + (g * 8 + j) * 4096];
        unsigned short h0 = f2bf(v0);
        ah0[j] = (short)h0; al0[j] = (short)f2bf(v0 - bf2f(h0));
        float v1 = x[xbase + (32 + g * 8 + j) * 4096];
        unsigned short h1 = f2bf(v1);
        ah1[j] = (short)h1; al1[j] = (short)f2bf(v1 - bf2f(h1));
    }

    unsigned best[4] = {~0u, ~0u, ~0u, ~0u}, sec[4] = {~0u, ~0u, ~0u, ~0u};
    const int tbase = c * 16;    // 16 tiles per chunk
    for (int ph = 0; ph < 2; ++ph) {
        // stage 8 tiles (32 KB) cooperatively
        const f32x4* src =
            (const f32x4*)(epack + (size_t)(tbase + ph * 8) * 2048);
        f32x4* dst = (f32x4*)elds;
#pragma unroll
        for (int i = 0; i < 8; ++i) dst[tid + 256 * i] = src[tid + 256 * i];
        __syncthreads();
#pragma unroll 4
        for (int tt = 0; tt < 8; ++tt) {
            int code = (tbase + ph * 8 + tt) * 16 + col;
            const short8* bp = elds + tt * 256;
            short8 bh0 = bp[lane];        // h, d 0..31   (s=g)
            short8 bh1 = bp[64 + lane];   // h, d 32..63
            short8 bl0 = bp[128 + lane];  // l, d 0..31
            short8 bl1 = bp[192 + lane];  // l, d 32..63
            float sqv = sqnB21[code];
            f32x4 a0 = {0.f, 0.f, 0.f, 0.f}, a1 = {0.f, 0.f, 0.f, 0.f};
            a0 = __builtin_amdgcn_mfma_f32_16x16x32_bf16(ah0, bh0, a0, 0, 0, 0);
            a0 = __builtin_amdgcn_mfma_f32_16x16x32_bf16(ah1, bh1, a0, 0, 0, 0);
            a1 = __builtin_amdgcn_mfma_f32_16x16x32_bf16(ah0, bl0, a1, 0, 0, 0);
            a1 = __builtin_amdgcn_mfma_f32_16x16x32_bf16(al0, bh0, a1, 0, 0, 0);
            a1 = __builtin_amdgcn_mfma_f32_16x16x32_bf16(ah1, bl1, a1, 0, 0, 0);
            a1 = __builtin_amdgcn_mfma_f32_16x16x32_bf16(al1, bh1, a1, 0, 0, 0);
#pragma unroll
            for (int r = 0; r < 4; ++r) {
                float s = a0[r] + a1[r];
                unsigned u = (unsigned)fmaf(s, -2097152.0f, sqv);
                unsigned pk = (u << 10) | (unsigned)code;
                unsigned t = umax_(pk, best[r]);
                sec[r] = umin_(sec[r], t);
                best[r] = umin_(best[r], pk);
            }
        }
        __syncthreads();   // protect LDS before next stage overwrites
    }
    // reduce over the 16 code-columns (xor within 16-lane groups)
#pragma unroll
    for (int st = 1; st < 16; st <<= 1) {
#pragma unroll
        for (int r = 0; r < 4; ++r) {
            unsigned ob = __shfl_xor(best[r], st);
            unsigned os = __shfl_xor(sec[r], st);
            sec[r] = umin_(umin_(sec[r], os), umax_(best[r], ob));
            best[r] = umin_(best[r], ob);
        }
    }
    if (col == 0) {
        int rowbase = rb * 64 + w * 16 + g * 4;
#pragma unroll
        for (int r = 0; r < 4; ++r)
            pairP[c * N_ROWS + rowbase + r] = make_uint2(best[r], sec[r]);
    }
}

// ---------------------------------------------------------------------------
// F: merge the 4 chunk partials per row; write idx; flag near-ties.
// ---------------------------------------------------------------------------
__global__ void vq_flag_kernel(const uint2* __restrict__ pairP,
                               int* __restrict__ idxp,
                               int* __restrict__ flaglist,
                               int* __restrict__ flagcount) {
    int n = blockIdx.x * blockDim.x + threadIdx.x;  // 32768 threads
    uint2 p0 = pairP[n];
    unsigned b = p0.x, s = p0.y;
#pragma unroll
    for (int cc = 1; cc < KSPLIT; ++cc) {
        uint2 q = pairP[cc * N_ROWS + n];
        s = umin_(umin_(s, q.y), umax_(b, q.x));
        b = umin_(b, q.x);
    }
    idxp[n] = (int)(b & 1023u);
    if (((s >> 10) - (b >> 10)) < GAP_QUANTA) {
        int pos = atomicAdd(flagcount, 1);
        flaglist[pos] = n;
    }
}

// ---------------------------------------------------------------------------
// B: exact fp64 re-scan of flagged rows (one wave per row).
// ---------------------------------------------------------------------------
__global__ __launch_bounds__(256) void vq_recheck_kernel(
    const float* __restrict__ x, const float* __restrict__ emb,
    const int* __restrict__ flaglist, const int* __restrict__ flagcount,
    int* __restrict__ idxp) {
    int lane = threadIdx.x & 63;
    int gw = (blockIdx.x * blockDim.x + threadIdx.x) >> 6;  // 0..1023
    int nf = flagcount[0];
    int dg = lane & 3, kg = lane >> 2;
    for (int i = gw; i < nf; i += 1024) {
        int n = flaglist[i];
        const float* xp = x + ((n >> 12) * 262144 + (n & 4095) + dg * 16 * 4096);
        double xd[16];
#pragma unroll
        for (int j = 0; j < 16; ++j) xd[j] = (double)xp[j * 4096];
        double best = 1e300;
        int bi = 0;
        for (int j = 0; j < 64; ++j) {
            int k = kg * 64 + j;
            const float4* e4 = (const float4*)(emb + k * DIM + dg * 16);
            double u = 0.0;
#pragma unroll
            for (int q = 0; q < 4; ++q) {
                float4 ev = e4[q];
                double e0 = ev.x, e1 = ev.y, e2 = ev.z, e3 = ev.w;
                u += e0 * (0.5 * e0 - xd[q * 4 + 0]);
                u += e1 * (0.5 * e1 - xd[q * 4 + 1]);
                u += e2 * (0.5 * e2 - xd[q * 4 + 2]);
                u += e3 * (0.5 * e3 - xd[q * 4 + 3]);
            }
            u += __shfl_xor(u, 1);
            u += __shfl_xor(u, 2);
            if (u < best) { best = u; bi = k; }
        }
        for (int off = 4; off < 64; off <<= 1) {
            double ob = __shfl_down(best, off);
            int oi = __shfl_down(bi, off);
            if (ob < best) { best = ob; bi = oi; }
        }
        if (lane == 0) idxp[n] = bi;
    }
}

// ---------------------------------------------------------------------------
// Q: quantized gather (NCHW) + per-block loss partial + counts, PLUS zeroing
// of the scratch slab [0, SCR_FLOATS) of enc (epack/pairP dead now) and the
// 2-float tail. Must run AFTER flag reads pairP and BEFORE ones.
// ---------------------------------------------------------------------------
__global__ __launch_bounds__(256) void vq_qloss_kernel(
    const float* __restrict__ x, const float* __restrict__ emb,
    const int* __restrict__ idxp, float* __restrict__ out,
    int* __restrict__ counts, double* __restrict__ lossp,
    float* __restrict__ enc) {
    int tid = threadIdx.x;
    int bi = blockIdx.x;

    // zero scratch slab: 163845 f32x2 slots over 2048 blocks (80 each + rem)
    {
        f32x2 z2 = {0.f, 0.f};
        f32x2* zp = (f32x2*)enc;
        if (tid < 80) zp[bi * 80 + tid] = z2;
        if (bi == 0 && tid >= 80 && tid < 85) zp[163840 + (tid - 80)] = z2;
        if (bi == 0 && tid == 85) zp[(ENC_FLOATS - 2) / 2] = z2;  // tail
    }

    int r = tid & 15;
    int dg = tid >> 4;
    int n = bi * 16 + r;
    int ix = idxp[n];
    int xoff = (n >> 12) * 262144 + (n & 4095);
    float4 ev = *(const float4*)(emb + ix * DIM + dg * 4);
    float* qp = out + OUT_Q + xoff;
    float lsum = 0.f;
#pragma unroll
    for (int j = 0; j < 4; ++j) {
        int d = dg * 4 + j;
        float e = (&ev.x)[j];
        float xval = x[xoff + d * 4096];
        float df = e - xval;
        lsum += df * df;
        qp[d * 4096] = e;
    }
    if (dg == 0) atomicAdd(&counts[ix], 1);
    double ls = (double)lsum;
    for (int off = 32; off > 0; off >>= 1) ls += __shfl_down(ls, off);
    __shared__ double red[4];
    if ((tid & 63) == 0) red[tid >> 6] = ls;
    __syncthreads();
    if (tid == 0) lossp[bi] = red[0] + red[1] + red[2] + red[3];
}

// ---------------------------------------------------------------------------
// E/D fused: scatter the 32768 ones; block 0 also computes perplexity+loss
// scalars (counts/lossp are complete after qloss).
// ---------------------------------------------------------------------------
__global__ __launch_bounds__(256) void vq_onesfin_kernel(
    const int* __restrict__ idxp, const int* __restrict__ counts,
    const double* __restrict__ lossp, float* __restrict__ enc,
    float* __restrict__ out) {
    int tid = threadIdx.x, bi = blockIdx.x;  // 128 x 256
    int n = bi * 256 + tid;
    enc[(size_t)n * 1024 + idxp[n]] = 1.0f;
    if (bi != 0) return;
    double v = 0.0, l = 0.0;
#pragma unroll
    for (int i = 0; i < 4; ++i) {
        double p = (double)counts[tid * 4 + i] / 32768.0;
        v += p * log(p + 1e-10);
    }
#pragma unroll
    for (int i = 0; i < 8; ++i) l += lossp[tid * 8 + i];
    for (int off = 32; off > 0; off >>= 1) {
        v += __shfl_down(v, off);
        l += __shfl_down(l, off);
    }
    __shared__ double redv[4], redl[4];
    if ((tid & 63) == 0) { redv[tid >> 6] = v; redl[tid >> 6] = l; }
    __syncthreads();
    if (tid == 0) {
        double sv = redv[0] + redv[1] + redv[2] + redv[3];
        double sl = redl[0] + redl[1] + redl[2] + redl[3];
        out[OUT_PERP] = (float)exp(-sv);
        out[0] = (float)(sl * (1.25 / 2097152.0));
    }
}

// ---------------------------------------------------------------------------
extern "C" void kernel_launch(void* const* d_in, const int* in_sizes, int n_in,
                              void* d_out, int out_size, void* d_ws,
                              size_t ws_size, hipStream_t stream) {
    (void)in_sizes; (void)n_in; (void)out_size; (void)ws_size;
    const float* x = (const float*)d_in[0];
    const float* emb = (const float*)d_in[1];
    float* out = (float*)d_out;
    char* p = (char*)d_ws;

    int* idxp = (int*)p;       p += 131072;
    int* flaglist = (int*)p;   p += 131072;
    float* sqnB21 = (float*)p; p += 4096;
    int* counts = (int*)p;     p += 4096;
    double* lossp = (double*)p; p += 16384;  // 2048 per-block partials
    int* flagcount = (int*)p;

    // scratch inside enc region (zeroed by qloss after use):
    float* enc = out + OUT_ENC;
    unsigned short* epack = (unsigned short*)(enc + 6);   // 256 KB
    uint2* pairP = (uint2*)(epack + 64 * 2048);           // 1 MB

    vq_prep_kernel<<<64, 256, 0, stream>>>(emb, sqnB21, epack, counts,
                                           flagcount);
    vq_argmin_mfma<<<512 * KSPLIT + ZBLOCKS, 256, 0, stream>>>(
        x, epack, sqnB21, pairP, enc);
    vq_flag_kernel<<<128, 256, 0, stream>>>(pairP, idxp, flaglist, flagcount);
    vq_recheck_kernel<<<256, 256, 0, stream>>>(x, emb, flaglist, flagcount,
                                               idxp);
    vq_qloss_kernel<<<2048, 256, 0, stream>>>(x, emb, idxp, out, counts,
                                              lossp, enc);
    vq_onesfin_kernel<<<128, 256, 0, stream>>>(idxp, counts, lossp, enc, out);
}